// Round 10
// baseline (756.059 us; speedup 1.0000x reference)
//
#include <hip/hip_runtime.h>
#include <hip/hip_fp16.h>

#define HID 32
#define LEAKY 0.01f
#define SE3NORM 0.17677669529663687f   // 1/sqrt(32)
#define SCAN_TILE 1024                 // elements per scan block (256 thr x 4)
#define NBK 128                        // dst nodes per bucket
#define GA 256                         // pass-A blocks

// ======================= bucket build: hist -> scan -> scatter =======================

// per-block LDS histogram of bucket (dst>>7); bh[b*GA + g] = count
__global__ void k_bhist(const int* __restrict__ ei, int* __restrict__ bh,
                        int E, int B1, int chunk) {
    extern __shared__ int lh[];                 // B1 ints
    int g = blockIdx.x;
    for (int i = threadIdx.x; i < B1; i += 256) lh[i] = 0;
    __syncthreads();
    int beg = g * chunk, end = min(E, beg + chunk);
    for (int e = beg + (int)threadIdx.x; e < end; e += 256)
        atomicAdd(&lh[ei[E + e] >> 7], 1);
    __syncthreads();
    for (int b = threadIdx.x; b < B1; b += 256) bh[b * GA + g] = lh[b];
}

__global__ void k_scan1(int* __restrict__ data, int* __restrict__ bsum, int M) {
    __shared__ int lds[256];
    int t = threadIdx.x;
    int base = blockIdx.x * SCAN_TILE + t * 4;
    int v0 = (base + 0 < M) ? data[base + 0] : 0;
    int v1 = (base + 1 < M) ? data[base + 1] : 0;
    int v2 = (base + 2 < M) ? data[base + 2] : 0;
    int v3 = (base + 3 < M) ? data[base + 3] : 0;
    int s = v0 + v1 + v2 + v3;
    lds[t] = s;
    __syncthreads();
    for (int off = 1; off < 256; off <<= 1) {
        int x = (t >= off) ? lds[t - off] : 0;
        __syncthreads();
        lds[t] += x;
        __syncthreads();
    }
    int ex = lds[t] - s;
    if (base + 0 < M) data[base + 0] = ex;
    if (base + 1 < M) data[base + 1] = ex + v0;
    if (base + 2 < M) data[base + 2] = ex + v0 + v1;
    if (base + 3 < M) data[base + 3] = ex + v0 + v1 + v2;
    if (t == 255) bsum[blockIdx.x] = lds[255];
}

__global__ void k_scan2(int* __restrict__ bsum, int B) {
    __shared__ int lds[256];
    int t = threadIdx.x;
    int base = t * 4;
    int v0 = (base + 0 < B) ? bsum[base + 0] : 0;
    int v1 = (base + 1 < B) ? bsum[base + 1] : 0;
    int v2 = (base + 2 < B) ? bsum[base + 2] : 0;
    int v3 = (base + 3 < B) ? bsum[base + 3] : 0;
    int s = v0 + v1 + v2 + v3;
    lds[t] = s;
    __syncthreads();
    for (int off = 1; off < 256; off <<= 1) {
        int x = (t >= off) ? lds[t - off] : 0;
        __syncthreads();
        lds[t] += x;
        __syncthreads();
    }
    int ex = lds[t] - s;
    if (base + 0 < B) bsum[base + 0] = ex;
    if (base + 1 < B) bsum[base + 1] = ex + v0;
    if (base + 2 < B) bsum[base + 2] = ex + v0 + v1;
    if (base + 3 < B) bsum[base + 3] = ex + v0 + v1 + v2;
}

__global__ void k_scan3(int* __restrict__ data, const int* __restrict__ bsum, int M) {
    int i = blockIdx.x * blockDim.x + threadIdx.x;
    if (i >= M) return;
    data[i] += bsum[i / SCAN_TILE];
}

// scatter edges into buckets via LDS cursors; pack (localdst<<24)|src  (src < 2^24)
__global__ void k_bscatter(const int* __restrict__ ei, const int* __restrict__ bh,
                           int* __restrict__ bucketed, int E, int B1, int chunk) {
    extern __shared__ int cur[];                // B1 ints
    int g = blockIdx.x;
    for (int b = threadIdx.x; b < B1; b += 256) cur[b] = bh[b * GA + g];
    __syncthreads();
    int beg = g * chunk, end = min(E, beg + chunk);
    for (int e = beg + (int)threadIdx.x; e < end; e += 256) {
        int d = ei[E + e];
        int s = ei[e];
        int b = d >> 7;
        int p = atomicAdd(&cur[b], 1);          // LDS atomic; slices disjoint per (b,g)
        bucketed[p] = s | ((d & (NBK - 1)) << 24);
    }
}

// ======================= layer 1: per-bucket pos aggregation + h1 MLP -> fp16 =======================
__global__ __launch_bounds__(256)
void k_layer1(const int* __restrict__ bh, const int* __restrict__ bucketed,
              const float* __restrict__ pos,
              const float* __restrict__ Wl1, const float* __restrict__ bl1,
              const float* __restrict__ Wr1, const float* __restrict__ Wse1,
              __half* __restrict__ h1, int E, int N, int B1) {
    __shared__ float sWl1[2 * HID], sWr1[2 * HID], sbl1[HID], sWse1[HID * HID];
    __shared__ float a01[NBK][2];
    const int b = blockIdx.x, tid = threadIdx.x;
    for (int i = tid; i < 2 * HID; i += 256) { sWl1[i] = Wl1[i]; sWr1[i] = Wr1[i]; }
    if (tid < HID) sbl1[tid] = bl1[tid];
    for (int i = tid; i < HID * HID; i += 256) sWse1[i] = Wse1[i];
    for (int i = tid; i < NBK * 2; i += 256) ((float*)a01)[i] = 0.f;
    __syncthreads();

    const int bs = bh[b * GA];
    const int be = (b == B1 - 1) ? E : bh[(b + 1) * GA];
    int e = bs + tid;
    for (; e + 3 * 256 < be; e += 4 * 256) {
        int pv0 = bucketed[e], pv1 = bucketed[e + 256];
        int pv2 = bucketed[e + 512], pv3 = bucketed[e + 768];
        int s0 = pv0 & 0xFFFFFF, s1 = pv1 & 0xFFFFFF, s2 = pv2 & 0xFFFFFF, s3 = pv3 & 0xFFFFFF;
        float x0 = pos[s0 * 3], y0 = pos[s0 * 3 + 1];
        float x1 = pos[s1 * 3], y1 = pos[s1 * 3 + 1];
        float x2 = pos[s2 * 3], y2 = pos[s2 * 3 + 1];
        float x3 = pos[s3 * 3], y3 = pos[s3 * 3 + 1];
        atomicAdd(&a01[pv0 >> 24][0], x0); atomicAdd(&a01[pv0 >> 24][1], y0);
        atomicAdd(&a01[pv1 >> 24][0], x1); atomicAdd(&a01[pv1 >> 24][1], y1);
        atomicAdd(&a01[pv2 >> 24][0], x2); atomicAdd(&a01[pv2 >> 24][1], y2);
        atomicAdd(&a01[pv3 >> 24][0], x3); atomicAdd(&a01[pv3 >> 24][1], y3);
    }
    for (; e < be; e += 256) {
        int pv = bucketed[e];
        int s = pv & 0xFFFFFF;
        atomicAdd(&a01[pv >> 24][0], pos[s * 3]);
        atomicAdd(&a01[pv >> 24][1], pos[s * 3 + 1]);
    }
    __syncthreads();

    if (tid < NBK) {
        int node = b * NBK + tid;
        if (node < N) {
            float a0 = a01[tid][0], a1 = a01[tid][1];
            float x0 = pos[node * 3], x1 = pos[node * 3 + 1];
            float h[HID];
#pragma unroll
            for (int j = 0; j < HID; j++) {
                float v = a0 * sWl1[j] + a1 * sWl1[HID + j] + sbl1[j]
                        + x0 * sWr1[j] + x1 * sWr1[HID + j];
                h[j] = v > 0.f ? v : LEAKY * v;
            }
            union Pack8 { __half h[8]; float4 v; };
#pragma unroll
            for (int c = 0; c < HID / 8; c++) {
                Pack8 p;
#pragma unroll
                for (int jj = 0; jj < 8; jj++) {
                    int j = c * 8 + jj;
                    float acc = 0.f;
#pragma unroll
                    for (int k = 0; k < HID; k++) acc += h[k] * sWse1[k * HID + j];
                    p.h[jj] = __float2half(acc * SE3NORM);
                }
                *(float4*)&h1[(size_t)node * HID + c * 8] = p.v;
            }
        }
    }
}

// ======================= layer 2 + head: per-bucket h1 aggregation + full head -> out =======================
__global__ __launch_bounds__(256)
void k_layer2(const int* __restrict__ bh, const int* __restrict__ bucketed,
              const __half* __restrict__ h1,
              const float* __restrict__ Wl2, const float* __restrict__ bl2,
              const float* __restrict__ Wr2, const float* __restrict__ Wse2,
              const float* __restrict__ W3, const float* __restrict__ b3,
              const float* __restrict__ W4, const float* __restrict__ b4,
              const float* __restrict__ alpha_p,
              float* __restrict__ out, int E, int N, int B1) {
    __shared__ float sWl2[HID * HID], sWr2[HID * HID], sWse2[HID * HID], sW3[HID * HID];
    __shared__ float sbl2[HID], sb3[HID], sW4[HID];
    __shared__ float sb4, salpha;
    __shared__ float acc[NBK][HID + 1];   // agg2, then h2
    __shared__ float sH1[NBK][HID + 1];   // own h1, then skip
    const int b = blockIdx.x, tid = threadIdx.x;
    const int base = b * NBK;
    for (int i = tid; i < HID * HID; i += 256) {
        sWl2[i] = Wl2[i]; sWr2[i] = Wr2[i]; sWse2[i] = Wse2[i]; sW3[i] = W3[i];
    }
    if (tid < HID) { sbl2[tid] = bl2[tid]; sb3[tid] = b3[tid]; sW4[tid] = W4[tid]; }
    if (tid == 0) { sb4 = b4[0]; salpha = alpha_p[0]; }
    for (int i = tid; i < NBK * HID; i += 256) {
        int n = i >> 5, k = i & 31;
        acc[n][k] = 0.f;
        int node = base + n;
        sH1[n][k] = (node < N) ? __half2float(h1[(size_t)node * HID + k]) : 0.f;
    }
    __syncthreads();

    const int bs = bh[b * GA];
    const int be = (b == B1 - 1) ? E : bh[(b + 1) * GA];
    const int grp = tid >> 3;             // 32 groups of 8 lanes
    const int t = tid & 7;                // 4 feats per lane
    int e = bs + grp;
    for (; e + 96 < be; e += 128) {
        int pv0 = bucketed[e],      pv1 = bucketed[e + 32];
        int pv2 = bucketed[e + 64], pv3 = bucketed[e + 96];
        float2 r0 = *(const float2*)&h1[(size_t)(pv0 & 0xFFFFFF) * HID + t * 4];
        float2 r1 = *(const float2*)&h1[(size_t)(pv1 & 0xFFFFFF) * HID + t * 4];
        float2 r2 = *(const float2*)&h1[(size_t)(pv2 & 0xFFFFFF) * HID + t * 4];
        float2 r3 = *(const float2*)&h1[(size_t)(pv3 & 0xFFFFFF) * HID + t * 4];
        const float2* rs[4] = {&r0, &r1, &r2, &r3};
        const int lds[4] = {pv0 >> 24, pv1 >> 24, pv2 >> 24, pv3 >> 24};
#pragma unroll
        for (int u = 0; u < 4; u++) {
            __half2 p01 = *(const __half2*)&rs[u]->x;
            __half2 p23 = *(const __half2*)&rs[u]->y;
            atomicAdd(&acc[lds[u]][t * 4 + 0], __low2float(p01));
            atomicAdd(&acc[lds[u]][t * 4 + 1], __high2float(p01));
            atomicAdd(&acc[lds[u]][t * 4 + 2], __low2float(p23));
            atomicAdd(&acc[lds[u]][t * 4 + 3], __high2float(p23));
        }
    }
    for (; e < be; e += 32) {
        int pv = bucketed[e];
        float2 rr = *(const float2*)&h1[(size_t)(pv & 0xFFFFFF) * HID + t * 4];
        __half2 p01 = *(const __half2*)&rr.x;
        __half2 p23 = *(const __half2*)&rr.y;
        int ld = pv >> 24;
        atomicAdd(&acc[ld][t * 4 + 0], __low2float(p01));
        atomicAdd(&acc[ld][t * 4 + 1], __high2float(p01));
        atomicAdd(&acc[ld][t * 4 + 2], __low2float(p23));
        atomicAdd(&acc[ld][t * 4 + 3], __high2float(p23));
    }
    __syncthreads();

    // head: each 8-lane group finishes 4 nodes; all row ops group-local (wave-lockstep safe)
    for (int nl = grp; nl < NBK; nl += 32) {
        int node = base + nl;
        if (node >= N) continue;
        float h2r[4];
#pragma unroll
        for (int jj = 0; jj < 4; jj++) {
            int j = t * 4 + jj;
            float a2 = sbl2[j];
#pragma unroll
            for (int k = 0; k < HID; k++)
                a2 += acc[nl][k] * sWl2[k * HID + j] + sH1[nl][k] * sWr2[k * HID + j];
            h2r[jj] = a2 > 0.f ? a2 : LEAKY * a2;
        }
#pragma unroll
        for (int jj = 0; jj < 4; jj++) acc[nl][t * 4 + jj] = h2r[jj];
        float skr[4];
#pragma unroll
        for (int jj = 0; jj < 4; jj++) {
            int j = t * 4 + jj;
            float a2 = 0.f;
#pragma unroll
            for (int k = 0; k < HID; k++) a2 += acc[nl][k] * sWse2[k * HID + j];
            skr[jj] = salpha * sH1[nl][j] + a2 * SE3NORM;
        }
#pragma unroll
        for (int jj = 0; jj < 4; jj++) sH1[nl][t * 4 + jj] = skr[jj];
        float part = 0.f;
#pragma unroll
        for (int jj = 0; jj < 4; jj++) {
            int j = t * 4 + jj;
            float a2 = sb3[j];
#pragma unroll
            for (int k = 0; k < HID; k++) a2 += sH1[nl][k] * sW3[k * HID + j];
            part += (a2 > 0.f ? a2 : 0.f) * sW4[j];
        }
        part += __shfl_xor(part, 1);
        part += __shfl_xor(part, 2);
        part += __shfl_xor(part, 4);
        if (t == 0) out[node] = part + sb4;
    }
}

extern "C" void kernel_launch(void* const* d_in, const int* in_sizes, int n_in,
                              void* d_out, int out_size, void* d_ws, size_t ws_size,
                              hipStream_t stream) {
    const float* pos  = (const float*)d_in[0];
    const int*   ei   = (const int*)d_in[1];
    const float* Wl1  = (const float*)d_in[2];
    const float* bl1  = (const float*)d_in[3];
    const float* Wr1  = (const float*)d_in[4];
    const float* Wl2  = (const float*)d_in[5];
    const float* bl2  = (const float*)d_in[6];
    const float* Wr2  = (const float*)d_in[7];
    const float* Wse1 = (const float*)d_in[8];
    const float* Wse2 = (const float*)d_in[9];
    const float* W3   = (const float*)d_in[10];
    const float* b3   = (const float*)d_in[11];
    const float* W4   = (const float*)d_in[12];
    const float* b4   = (const float*)d_in[13];
    const float* alp  = (const float*)d_in[14];
    float* out = (float*)d_out;

    const int N = in_sizes[0] / 3;
    const int E = in_sizes[1] / 2;
    const int blk = 256;
    const int B1 = (N + NBK - 1) / NBK;
    const int M2 = B1 * GA;
    const int S2 = (M2 + SCAN_TILE - 1) / SCAN_TILE;

    // ws: bh[M2] bsum[1024] bucketed[E] | h1 fp16[N*HID]
    int* bh       = (int*)d_ws;
    int* bsum     = bh + M2;
    int* bucketed = bsum + 1024;
    uintptr_t hp = ((uintptr_t)(bucketed + E) + 15) & ~(uintptr_t)15;
    size_t need = (hp - (uintptr_t)d_ws) + (size_t)N * HID * sizeof(__half);
    if (need > ws_size || S2 > 1024) return;   // never expected (ws >= 34 MB proven R5-R9)
    __half* h1 = (__half*)hp;

    const int chunk = (E + GA - 1) / GA;
    const size_t ldsB = (size_t)B1 * sizeof(int);
    k_bhist<<<GA, 256, ldsB, stream>>>(ei, bh, E, B1, chunk);
    k_scan1<<<S2, 256, 0, stream>>>(bh, bsum, M2);
    k_scan2<<<1, 256, 0, stream>>>(bsum, S2);
    k_scan3<<<(M2 + blk - 1) / blk, blk, 0, stream>>>(bh, bsum, M2);
    k_bscatter<<<GA, 256, ldsB, stream>>>(ei, bh, bucketed, E, B1, chunk);
    k_layer1<<<B1, 256, 0, stream>>>(bh, bucketed, pos, Wl1, bl1, Wr1, Wse1, h1, E, N, B1);
    k_layer2<<<B1, 256, 0, stream>>>(bh, bucketed, h1, Wl2, bl2, Wr2, Wse2,
                                     W3, b3, W4, b4, alp, out, E, N, B1);
}

// Round 11
// 315.429 us; speedup vs baseline: 2.3969x; 2.3969x over previous
//
#include <hip/hip_runtime.h>
#include <hip/hip_fp16.h>

#define HID 32
#define LEAKY 0.01f
#define SE3NORM 0.17677669529663687f   // 1/sqrt(32)
#define SCAN_TILE 1024                 // elements per scan block (256 thr x 4)
#define NBK 128                        // dst nodes per coarse bucket
#define GA 256                         // pass-A blocks

typedef float vf4 __attribute__((ext_vector_type(4)));

// ======================= CSR build: coarse dst buckets (R6-proven) =======================

__global__ void k_bhist(const int* __restrict__ ei, int* __restrict__ bh,
                        int E, int B1, int chunk) {
    extern __shared__ int lh[];                 // B1 ints
    int g = blockIdx.x;
    for (int i = threadIdx.x; i < B1; i += 256) lh[i] = 0;
    __syncthreads();
    int beg = g * chunk, end = min(E, beg + chunk);
    for (int e = beg + (int)threadIdx.x; e < end; e += 256)
        atomicAdd(&lh[ei[E + e] >> 7], 1);
    __syncthreads();
    for (int b = threadIdx.x; b < B1; b += 256) bh[b * GA + g] = lh[b];
}

__global__ void k_scan1(int* __restrict__ data, int* __restrict__ bsum, int M) {
    __shared__ int lds[256];
    int t = threadIdx.x;
    int base = blockIdx.x * SCAN_TILE + t * 4;
    int v0 = (base + 0 < M) ? data[base + 0] : 0;
    int v1 = (base + 1 < M) ? data[base + 1] : 0;
    int v2 = (base + 2 < M) ? data[base + 2] : 0;
    int v3 = (base + 3 < M) ? data[base + 3] : 0;
    int s = v0 + v1 + v2 + v3;
    lds[t] = s;
    __syncthreads();
    for (int off = 1; off < 256; off <<= 1) {
        int x = (t >= off) ? lds[t - off] : 0;
        __syncthreads();
        lds[t] += x;
        __syncthreads();
    }
    int ex = lds[t] - s;
    if (base + 0 < M) data[base + 0] = ex;
    if (base + 1 < M) data[base + 1] = ex + v0;
    if (base + 2 < M) data[base + 2] = ex + v0 + v1;
    if (base + 3 < M) data[base + 3] = ex + v0 + v1 + v2;
    if (t == 255) bsum[blockIdx.x] = lds[255];
}

__global__ void k_scan2(int* __restrict__ bsum, int B) {
    __shared__ int lds[256];
    int t = threadIdx.x;
    int base = t * 4;
    int v0 = (base + 0 < B) ? bsum[base + 0] : 0;
    int v1 = (base + 1 < B) ? bsum[base + 1] : 0;
    int v2 = (base + 2 < B) ? bsum[base + 2] : 0;
    int v3 = (base + 3 < B) ? bsum[base + 3] : 0;
    int s = v0 + v1 + v2 + v3;
    lds[t] = s;
    __syncthreads();
    for (int off = 1; off < 256; off <<= 1) {
        int x = (t >= off) ? lds[t - off] : 0;
        __syncthreads();
        lds[t] += x;
        __syncthreads();
    }
    int ex = lds[t] - s;
    if (base + 0 < B) bsum[base + 0] = ex;
    if (base + 1 < B) bsum[base + 1] = ex + v0;
    if (base + 2 < B) bsum[base + 2] = ex + v0 + v1;
    if (base + 3 < B) bsum[base + 3] = ex + v0 + v1 + v2;
}

__global__ void k_scan3(int* __restrict__ data, const int* __restrict__ bsum, int M) {
    int i = blockIdx.x * blockDim.x + threadIdx.x;
    if (i >= M) return;
    data[i] += bsum[i / SCAN_TILE];
}

__global__ void k_bscatter(const int* __restrict__ ei, const int* __restrict__ bh,
                           int* __restrict__ bucketed, int E, int B1, int chunk) {
    extern __shared__ int cur[];                // B1 ints
    int g = blockIdx.x;
    for (int b = threadIdx.x; b < B1; b += 256) cur[b] = bh[b * GA + g];
    __syncthreads();
    int beg = g * chunk, end = min(E, beg + chunk);
    for (int e = beg + (int)threadIdx.x; e < end; e += 256) {
        int d = ei[E + e];
        int s = ei[e];
        int b = d >> 7;
        int p = atomicAdd(&cur[b], 1);          // LDS atomic; slices disjoint per (b,g)
        bucketed[p] = s | ((d & (NBK - 1)) << 24);
    }
}

// per-bucket 256-bin counting sort, bin = (localdst<<1)|(src>=half)
// -> sorted_src + node-major off2[node*2 + r]
__global__ void k_bsort(const int* __restrict__ bh, const int* __restrict__ bucketed,
                        int* __restrict__ sorted_src, int* __restrict__ off2,
                        int E, int N, int B1, int half) {
    __shared__ int hist[256], base[256], lds[256];
    int b = blockIdx.x;
    int t = threadIdx.x;
    int bs = bh[b * GA];
    int be = (b == B1 - 1) ? E : bh[(b + 1) * GA];
    hist[t] = 0;
    __syncthreads();
    for (int e = bs + t; e < be; e += 256) {
        int pv = bucketed[e];
        int bin = ((pv >> 24) << 1) | ((pv & 0x00FFFFFF) >= half);
        atomicAdd(&hist[bin], 1);
    }
    __syncthreads();
    int v = hist[t];
    lds[t] = v;
    __syncthreads();
    for (int off = 1; off < 256; off <<= 1) {
        int x = (t >= off) ? lds[t - off] : 0;
        __syncthreads();
        lds[t] += x;
        __syncthreads();
    }
    int ex = lds[t] - v;
    base[t] = ex;
    __syncthreads();
    hist[t] = ex;                               // cursor
    __syncthreads();
    for (int e = bs + t; e < be; e += 256) {
        int pv = bucketed[e];
        int bin = ((pv >> 24) << 1) | ((pv & 0x00FFFFFF) >= half);
        int p = atomicAdd(&hist[bin], 1);
        sorted_src[bs + p] = pv & 0x00FFFFFF;
    }
    int node = b * NBK + (t >> 1);
    if (node < N) off2[node * 2 + (t & 1)] = bs + base[t];
    if (b == B1 - 1 && t == 0) off2[2 * N] = E;
}

// ======================= node kernels =======================
// layer 1: agg1 over full segment [off2[2i], off2[2i+2]) + h1 MLP -> fp16
__global__ void k_node1(const int* __restrict__ off2, const int* __restrict__ sorted_src,
                        const float* __restrict__ pos,
                        const float* __restrict__ Wl1, const float* __restrict__ bl1,
                        const float* __restrict__ Wr1, const float* __restrict__ Wse1,
                        __half* __restrict__ h1out, int N) {
    __shared__ float sWl1[2 * HID], sWr1[2 * HID], sbl1[HID], sWse1[HID * HID];
    for (int i = threadIdx.x; i < 2 * HID; i += blockDim.x) { sWl1[i] = Wl1[i]; sWr1[i] = Wr1[i]; }
    for (int i = threadIdx.x; i < HID; i += blockDim.x) sbl1[i] = bl1[i];
    for (int i = threadIdx.x; i < HID * HID; i += blockDim.x) sWse1[i] = Wse1[i];
    __syncthreads();
    int i = blockIdx.x * blockDim.x + threadIdx.x;
    if (i >= N) return;
    int beg = off2[i * 2], end = off2[i * 2 + 2];
    float a0 = 0.f, a1 = 0.f;
    int e = beg;
    for (; e + 4 <= end; e += 4) {
        int s0 = sorted_src[e], s1 = sorted_src[e + 1], s2 = sorted_src[e + 2], s3 = sorted_src[e + 3];
        a0 += pos[s0 * 3] + pos[s1 * 3] + pos[s2 * 3] + pos[s3 * 3];
        a1 += pos[s0 * 3 + 1] + pos[s1 * 3 + 1] + pos[s2 * 3 + 1] + pos[s3 * 3 + 1];
    }
    for (; e < end; e++) {
        int s = sorted_src[e];
        a0 += pos[s * 3];
        a1 += pos[s * 3 + 1];
    }
    float x0 = pos[3 * i], x1 = pos[3 * i + 1];
    float h[HID];
#pragma unroll
    for (int j = 0; j < HID; j++) {
        float v = a0 * sWl1[j] + a1 * sWl1[HID + j] + sbl1[j] + x0 * sWr1[j] + x1 * sWr1[HID + j];
        h[j] = v > 0.f ? v : LEAKY * v;
    }
    union Pack8 { __half h[8]; float4 v; };
#pragma unroll
    for (int c = 0; c < HID / 8; c++) {
        Pack8 p;
#pragma unroll
        for (int jj = 0; jj < 8; jj++) {
            int j = c * 8 + jj;
            float acc = 0.f;
#pragma unroll
            for (int k = 0; k < HID; k++) acc += h[k] * sWse1[k * HID + j];
            p.h[jj] = __float2half(acc * SE3NORM);
        }
        *(float4*)&h1out[(size_t)i * HID + c * 8] = p.v;
    }
}

// phase 0: gather range-0 sub-segment, nontemporal store agg2
__global__ void k_agg0(const int* __restrict__ off2, const int* __restrict__ sorted_src,
                       const __half* __restrict__ h1, float* __restrict__ agg2, int N) {
    int lt = blockIdx.x * blockDim.x + threadIdx.x;
    int node = lt >> 3;
    int t = lt & 7;
    if (node >= N) return;
    int beg = off2[node * 2], end = off2[node * 2 + 1];
    float4 acc = make_float4(0.f, 0.f, 0.f, 0.f);
    int e = beg;
    for (; e + 4 <= end; e += 4) {
        int s0 = __builtin_nontemporal_load(&sorted_src[e]);
        int s1 = __builtin_nontemporal_load(&sorted_src[e + 1]);
        int s2 = __builtin_nontemporal_load(&sorted_src[e + 2]);
        int s3 = __builtin_nontemporal_load(&sorted_src[e + 3]);
        float2 r0 = *(const float2*)&h1[(size_t)s0 * HID + t * 4];
        float2 r1 = *(const float2*)&h1[(size_t)s1 * HID + t * 4];
        float2 r2 = *(const float2*)&h1[(size_t)s2 * HID + t * 4];
        float2 r3 = *(const float2*)&h1[(size_t)s3 * HID + t * 4];
        const float2* rs[4] = {&r0, &r1, &r2, &r3};
#pragma unroll
        for (int u = 0; u < 4; u++) {
            __half2 p01 = *(const __half2*)&rs[u]->x;
            __half2 p23 = *(const __half2*)&rs[u]->y;
            acc.x += __low2float(p01); acc.y += __high2float(p01);
            acc.z += __low2float(p23); acc.w += __high2float(p23);
        }
    }
    for (; e < end; e++) {
        int s = __builtin_nontemporal_load(&sorted_src[e]);
        float2 rr = *(const float2*)&h1[(size_t)s * HID + t * 4];
        __half2 p01 = *(const __half2*)&rr.x;
        __half2 p23 = *(const __half2*)&rr.y;
        acc.x += __low2float(p01); acc.y += __high2float(p01);
        acc.z += __low2float(p23); acc.w += __high2float(p23);
    }
    vf4 av; av.x = acc.x; av.y = acc.y; av.z = acc.z; av.w = acc.w;
    __builtin_nontemporal_store(av, (vf4*)&agg2[(size_t)node * HID + t * 4]);
}

// phase 1 + head: gather range-1, add nontemporal agg2, full head -> out
__global__ void k_agg1head(const int* __restrict__ off2, const int* __restrict__ sorted_src,
                           const __half* __restrict__ h1, const float* __restrict__ agg2,
                           const float* __restrict__ Wl2, const float* __restrict__ bl2,
                           const float* __restrict__ Wr2, const float* __restrict__ Wse2,
                           const float* __restrict__ W3, const float* __restrict__ b3,
                           const float* __restrict__ W4, const float* __restrict__ b4,
                           const float* __restrict__ alpha_p,
                           float* __restrict__ out, int N) {
    __shared__ float sWl2[HID * HID], sWr2[HID * HID], sWse2[HID * HID], sW3[HID * HID];
    __shared__ float sbl2[HID], sb3[HID], sW4[HID];
    __shared__ float sb4, salpha;
    __shared__ float sA[32][HID + 1], sB[32][HID + 1];
    for (int i = threadIdx.x; i < HID * HID; i += blockDim.x) {
        sWl2[i] = Wl2[i]; sWr2[i] = Wr2[i]; sWse2[i] = Wse2[i]; sW3[i] = W3[i];
    }
    for (int i = threadIdx.x; i < HID; i += blockDim.x) { sbl2[i] = bl2[i]; sb3[i] = b3[i]; sW4[i] = W4[i]; }
    if (threadIdx.x == 0) { sb4 = b4[0]; salpha = alpha_p[0]; }
    __syncthreads();

    const int lt = threadIdx.x;
    const int nodeL = lt >> 3;
    const int t = lt & 7;
    const int node = blockIdx.x * 32 + nodeL;
    const bool live = node < N;

    float hvr[4];
    if (live) {
        // accumulated phase-0 partial (streamed, read once)
        vf4 p0 = __builtin_nontemporal_load((const vf4*)&agg2[(size_t)node * HID + t * 4]);
        float4 acc = make_float4(p0.x, p0.y, p0.z, p0.w);
        int beg = off2[node * 2 + 1], end = off2[node * 2 + 2];
        int e = beg;
        for (; e + 4 <= end; e += 4) {
            int s0 = __builtin_nontemporal_load(&sorted_src[e]);
            int s1 = __builtin_nontemporal_load(&sorted_src[e + 1]);
            int s2 = __builtin_nontemporal_load(&sorted_src[e + 2]);
            int s3 = __builtin_nontemporal_load(&sorted_src[e + 3]);
            float2 r0 = *(const float2*)&h1[(size_t)s0 * HID + t * 4];
            float2 r1 = *(const float2*)&h1[(size_t)s1 * HID + t * 4];
            float2 r2 = *(const float2*)&h1[(size_t)s2 * HID + t * 4];
            float2 r3 = *(const float2*)&h1[(size_t)s3 * HID + t * 4];
            const float2* rs[4] = {&r0, &r1, &r2, &r3};
#pragma unroll
            for (int u = 0; u < 4; u++) {
                __half2 p01 = *(const __half2*)&rs[u]->x;
                __half2 p23 = *(const __half2*)&rs[u]->y;
                acc.x += __low2float(p01); acc.y += __high2float(p01);
                acc.z += __low2float(p23); acc.w += __high2float(p23);
            }
        }
        for (; e < end; e++) {
            int s = __builtin_nontemporal_load(&sorted_src[e]);
            float2 rr = *(const float2*)&h1[(size_t)s * HID + t * 4];
            __half2 p01 = *(const __half2*)&rr.x;
            __half2 p23 = *(const __half2*)&rr.y;
            acc.x += __low2float(p01); acc.y += __high2float(p01);
            acc.z += __low2float(p23); acc.w += __high2float(p23);
        }
        float2 ro = *(const float2*)&h1[(size_t)node * HID + t * 4];
        __half2 o01 = *(const __half2*)&ro.x;
        __half2 o23 = *(const __half2*)&ro.y;
        hvr[0] = __low2float(o01); hvr[1] = __high2float(o01);
        hvr[2] = __low2float(o23); hvr[3] = __high2float(o23);
        sA[nodeL][t * 4 + 0] = acc.x; sA[nodeL][t * 4 + 1] = acc.y;
        sA[nodeL][t * 4 + 2] = acc.z; sA[nodeL][t * 4 + 3] = acc.w;
        sB[nodeL][t * 4 + 0] = hvr[0]; sB[nodeL][t * 4 + 1] = hvr[1];
        sB[nodeL][t * 4 + 2] = hvr[2]; sB[nodeL][t * 4 + 3] = hvr[3];
    }
    __syncthreads();

    float h2r[4];
    if (live) {
#pragma unroll
        for (int jj = 0; jj < 4; jj++) {
            int j = t * 4 + jj;
            float a2 = sbl2[j];
#pragma unroll
            for (int k = 0; k < HID; k++)
                a2 += sA[nodeL][k] * sWl2[k * HID + j] + sB[nodeL][k] * sWr2[k * HID + j];
            h2r[jj] = a2 > 0.f ? a2 : LEAKY * a2;
        }
    }
    __syncthreads();
    if (live) {
#pragma unroll
        for (int jj = 0; jj < 4; jj++) sA[nodeL][t * 4 + jj] = h2r[jj];
    }
    __syncthreads();
    if (live) {
#pragma unroll
        for (int jj = 0; jj < 4; jj++) {
            int j = t * 4 + jj;
            float a2 = 0.f;
#pragma unroll
            for (int k = 0; k < HID; k++) a2 += sA[nodeL][k] * sWse2[k * HID + j];
            sB[nodeL][j] = salpha * hvr[jj] + a2 * SE3NORM;
        }
    }
    __syncthreads();
    float part = 0.f;
#pragma unroll
    for (int jj = 0; jj < 4; jj++) {
        int j = t * 4 + jj;
        float a2 = sb3[j];
        if (live) {
#pragma unroll
            for (int k = 0; k < HID; k++) a2 += sB[nodeL][k] * sW3[k * HID + j];
        }
        part += (a2 > 0.f ? a2 : 0.f) * sW4[j];
    }
    part += __shfl_xor(part, 1);
    part += __shfl_xor(part, 2);
    part += __shfl_xor(part, 4);
    if (live && t == 0) out[node] = part + sb4;
}

extern "C" void kernel_launch(void* const* d_in, const int* in_sizes, int n_in,
                              void* d_out, int out_size, void* d_ws, size_t ws_size,
                              hipStream_t stream) {
    const float* pos  = (const float*)d_in[0];
    const int*   ei   = (const int*)d_in[1];
    const float* Wl1  = (const float*)d_in[2];
    const float* bl1  = (const float*)d_in[3];
    const float* Wr1  = (const float*)d_in[4];
    const float* Wl2  = (const float*)d_in[5];
    const float* bl2  = (const float*)d_in[6];
    const float* Wr2  = (const float*)d_in[7];
    const float* Wse1 = (const float*)d_in[8];
    const float* Wse2 = (const float*)d_in[9];
    const float* W3   = (const float*)d_in[10];
    const float* b3   = (const float*)d_in[11];
    const float* W4   = (const float*)d_in[12];
    const float* b4   = (const float*)d_in[13];
    const float* alp  = (const float*)d_in[14];
    float* out = (float*)d_out;

    const int N = in_sizes[0] / 3;
    const int E = in_sizes[1] / 2;
    const int blk = 256;
    const int half = (N + 1) / 2;
    const int B1 = (N + NBK - 1) / NBK;
    const int M2 = B1 * GA;
    const int S2 = (M2 + SCAN_TILE - 1) / SCAN_TILE;

    // ws: bh[M2] bsum[1024] region[max(E, N*HID)] sorted_src[E] off2[2N+1] | h1 fp16
    int* bh         = (int*)d_ws;
    int* bsum       = bh + M2;
    int* region     = bsum + 1024;
    size_t regionInts = (size_t)E > (size_t)N * HID ? (size_t)E : (size_t)N * HID;
    int* sorted_src = region + regionInts;
    int* off2       = sorted_src + E;
    uintptr_t hp = ((uintptr_t)(off2 + (size_t)2 * N + 1) + 15) & ~(uintptr_t)15;
    size_t need = (hp - (uintptr_t)d_ws) + (size_t)N * HID * sizeof(__half);
    if (need > ws_size || S2 > 1024) return;   // ws ~31 MB; ≥34 MB proven available R5-R9
    int* bucketed = region;                     // build phase
    float* agg2   = (float*)region;             // aliased after bsort (bucketed dead)
    __half* h1    = (__half*)hp;

    const int chunk = (E + GA - 1) / GA;
    const size_t ldsB = (size_t)B1 * sizeof(int);
    k_bhist<<<GA, 256, ldsB, stream>>>(ei, bh, E, B1, chunk);
    k_scan1<<<S2, 256, 0, stream>>>(bh, bsum, M2);
    k_scan2<<<1, 256, 0, stream>>>(bsum, S2);
    k_scan3<<<(M2 + blk - 1) / blk, blk, 0, stream>>>(bh, bsum, M2);
    k_bscatter<<<GA, 256, ldsB, stream>>>(ei, bh, bucketed, E, B1, chunk);
    k_bsort<<<B1, 256, 0, stream>>>(bh, bucketed, sorted_src, off2, E, N, B1, half);
    k_node1<<<(N + blk - 1) / blk, blk, 0, stream>>>(off2, sorted_src, pos,
                                                     Wl1, bl1, Wr1, Wse1, h1, N);
    const int agrid = ((N * 8) + blk - 1) / blk;
    k_agg0<<<agrid, blk, 0, stream>>>(off2, sorted_src, h1, agg2, N);
    k_agg1head<<<(N + 31) / 32, 256, 0, stream>>>(off2, sorted_src, h1, agg2,
                                                  Wl2, bl2, Wr2, Wse2,
                                                  W3, b3, W4, b4, alp, out, N);
}